// Round 8
// baseline (439.794 us; speedup 1.0000x reference)
//
#include <hip/hip_runtime.h>
#include <hip/hip_bf16.h>

// Shapes (fixed by the problem)
#define B_  2
#define S_  2048
#define D_  1024
#define H_  16
#define HD_ 64
#define FF_ 4096
#define NT  (B_ * S_)          // 4096 tokens
#define SCALE_ 0.125f          // 1/sqrt(64)
#define KLOG2E 0.1803368801111f // SCALE * log2(e)
#define EPS_  1e-5f

typedef __attribute__((ext_vector_type(8))) short bf16x8;   // 8 bf16 = 4 VGPRs
typedef __attribute__((ext_vector_type(4))) float f32x4;    // MFMA C/D frag

__device__ inline short f2bf(float f) {
    __hip_bfloat16 h = __float2bfloat16(f);
    return __builtin_bit_cast(short, h);
}
__device__ inline float bf2f(unsigned short u) {
    __hip_bfloat16 h = __builtin_bit_cast(__hip_bfloat16, u);
    return __bfloat162float(h);
}

#define GLOBAL_AS __attribute__((address_space(1)))
#define LDS_AS    __attribute__((address_space(3)))

// ---------------------------------------------------------------------------
// Dtype detection (verified working)
// ---------------------------------------------------------------------------
struct DetectArgs { const unsigned short* p[12]; int n[12]; };

__global__ __launch_bounds__(256) void detect_kernel(DetectArgs a, int* flags) {
    const int t = blockIdx.x;
    const unsigned short* s = a.p[t];
    const int cnt = min(a.n[t], 16384);
    const int tid = threadIdx.x;
    int huge = 0, zeven = 0;
    for (int i = tid; i < cnt; i += 256) {
        const unsigned short v = s[i];
        const int e = (v >> 7) & 0xFF;
        if (e >= 142) huge++;
        if (((i & 1) == 0) && ((v & 0x7FFF) == 0)) zeven++;
    }
    __shared__ int sh, sz;
    if (tid == 0) { sh = 0; sz = 0; }
    __syncthreads();
    atomicAdd(&sh, huge);
    atomicAdd(&sz, zeven);
    __syncthreads();
    if (tid == 0) flags[t] = (sh > 0 || sz * 4 > cnt) ? 1 : 0;
}

__global__ __launch_bounds__(256) void conv_bf16_kernel(
    const void* __restrict__ src, unsigned short* __restrict__ dst, int n,
    const int* __restrict__ flags, int fidx)
{
    const int i = blockIdx.x * 256 + threadIdx.x;
    if (i >= n) return;
    if (flags[fidx])
        dst[i] = (unsigned short)f2bf(((const float*)src)[i]);
    else
        dst[i] = ((const unsigned short*)src)[i];
}

// tiled transpose convert: src [K,N] (f32 or bf16) -> dst [N,K] bf16
__global__ __launch_bounds__(256) void conv_t_kernel(
    const void* __restrict__ src, unsigned short* __restrict__ dst,
    int K, int N, const int* __restrict__ flags, int fidx)
{
    __shared__ short T[32][33];
    const int kt = blockIdx.x * 32, nt = blockIdx.y * 32;
    const int c  = threadIdx.x & 31;
    const int r0 = (threadIdx.x >> 5) * 4;
    const int f  = flags[fidx];
#pragma unroll
    for (int i = 0; i < 4; i++) {
        const int r = r0 + i;
        const size_t gi = (size_t)(kt + r) * N + nt + c;
        short v = f ? f2bf(((const float*)src)[gi])
                    : (short)((const unsigned short*)src)[gi];
        T[c][r] = v;
    }
    __syncthreads();
#pragma unroll
    for (int i = 0; i < 4; i++) {
        const int n = r0 + i;
        dst[(size_t)(nt + n) * K + kt + c] = (unsigned short)T[n][c];
    }
}

struct VecArgs { const void* src[7]; float* dst[7]; int n[7]; int fidx[7]; };

__global__ __launch_bounds__(256) void conv_vecs_kernel(VecArgs a,
                                                        const int* __restrict__ flags) {
#pragma unroll
    for (int v = 0; v < 7; v++) {
        const int f = flags[a.fidx[v]];
        for (int i = blockIdx.x * 256 + threadIdx.x; i < a.n[v]; i += gridDim.x * 256) {
            a.dst[v][i] = f ? ((const float*)a.src[v])[i]
                            : bf2f(((const unsigned short*)a.src[v])[i]);
        }
    }
}

// ---------------------------------------------------------------------------
// 128x128 MFMA GEMM (m97 structure) — verified.
// QSCALE: scale Q-part cols of the qkv projection by KLOG2E.
// ---------------------------------------------------------------------------
template<bool HAS_BIAS, bool RELU, int RES, bool OUT_F32, bool QSCALE>
__global__ __launch_bounds__(256) void gemm128_kernel(
    const unsigned short* __restrict__ A,
    const unsigned short* __restrict__ Bt,
    const float* __restrict__ bias,
    const unsigned short* __restrict__ resb,
    const float* __restrict__ resf,
    const int* __restrict__ flags,
    void* __restrict__ out,
    int M, int N, int K)
{
    __shared__ short As[128 * 32];
    __shared__ short Bs[128 * 32];

    const int tid  = threadIdx.x;
    const int wave = tid >> 6;
    const int lane = tid & 63;
    const int quad = lane >> 4;
    const int l16  = lane & 15;

    const int row0 = blockIdx.x * 128;
    const int col0 = blockIdx.y * 128;

    const int ldrow = lane >> 2;
    const int ldk   = (lane & 3) * 8;
    const unsigned short* agp0 = A  + (size_t)(row0 + wave * 32 + ldrow) * K + ldk;
    const unsigned short* agp1 = agp0 + (size_t)16 * K;
    const unsigned short* bgp0 = Bt + (size_t)(col0 + wave * 32 + ldrow) * K + ldk;
    const unsigned short* bgp1 = bgp0 + (size_t)16 * K;
    LDS_AS void* alds0 = (LDS_AS void*)&As[wave * 1024 + lane * 8];
    LDS_AS void* alds1 = (LDS_AS void*)&As[wave * 1024 + 512 + lane * 8];
    LDS_AS void* blds0 = (LDS_AS void*)&Bs[wave * 1024 + lane * 8];
    LDS_AS void* blds1 = (LDS_AS void*)&Bs[wave * 1024 + 512 + lane * 8];

    const int wm = (wave >> 1) * 64;
    const int wn = (wave & 1) * 64;

    f32x4 acc[4][4] = {};

    for (int k0 = 0; k0 < K; k0 += 32) {
        __builtin_amdgcn_global_load_lds(
            (const GLOBAL_AS void*)(agp0 + k0), alds0, 16, 0, 0);
        __builtin_amdgcn_global_load_lds(
            (const GLOBAL_AS void*)(agp1 + k0), alds1, 16, 0, 0);
        __builtin_amdgcn_global_load_lds(
            (const GLOBAL_AS void*)(bgp0 + k0), blds0, 16, 0, 0);
        __builtin_amdgcn_global_load_lds(
            (const GLOBAL_AS void*)(bgp1 + k0), blds1, 16, 0, 0);
        __syncthreads();

        bf16x8 af[4], bfr[4];
#pragma unroll
        for (int mi = 0; mi < 4; mi++)
            af[mi] = *reinterpret_cast<const bf16x8*>(
                &As[(wm + mi * 16 + l16) * 32 + quad * 8]);
#pragma unroll
        for (int ni = 0; ni < 4; ni++)
            bfr[ni] = *reinterpret_cast<const bf16x8*>(
                &Bs[(wn + ni * 16 + l16) * 32 + quad * 8]);
#pragma unroll
        for (int mi = 0; mi < 4; mi++)
#pragma unroll
            for (int ni = 0; ni < 4; ni++)
                acc[mi][ni] = __builtin_amdgcn_mfma_f32_16x16x32_bf16(
                    af[mi], bfr[ni], acc[mi][ni], 0, 0, 0);
        __syncthreads();
    }

    int resIsF32 = 0;
    if constexpr (RES == 2) resIsF32 = flags[0];

#pragma unroll
    for (int ni = 0; ni < 4; ni++) {
        const int col = col0 + wn + ni * 16 + l16;
        float badd = 0.f;
        if constexpr (HAS_BIAS) badd = bias[col];
        float qs = 1.f;
        if constexpr (QSCALE)
            qs = (((col0 + wn + ni * 16) % 192) < 64) ? KLOG2E : 1.f;
#pragma unroll
        for (int mi = 0; mi < 4; mi++) {
#pragma unroll
            for (int r = 0; r < 4; r++) {
                const int row = row0 + wm + mi * 16 + quad * 4 + r;
                float v = acc[mi][ni][r] + badd;
                if constexpr (QSCALE) v *= qs;
                if constexpr (RES == 1) {
                    v += bf2f(resb[(size_t)row * N + col]);
                } else if constexpr (RES == 2) {
                    v += resIsF32 ? resf[(size_t)row * N + col]
                                  : bf2f(resb[(size_t)row * N + col]);
                }
                if constexpr (RELU) v = fmaxf(v, 0.f);
                if constexpr (OUT_F32)
                    ((float*)out)[(size_t)row * N + col] = v;
                else
                    ((unsigned short*)out)[(size_t)row * N + col] =
                        (unsigned short)f2bf(v);
            }
        }
    }
}

// ---------------------------------------------------------------------------
// Split-K 128x128 GEMM: blockIdx.z selects K-half; raw f32 partials.
// ---------------------------------------------------------------------------
__global__ __launch_bounds__(256) void gemm128_sk_kernel(
    const unsigned short* __restrict__ A,
    const unsigned short* __restrict__ Bt,
    float* __restrict__ out0,
    float* __restrict__ out1,
    int M, int N, int K)
{
    __shared__ short As[128 * 32];
    __shared__ short Bs[128 * 32];

    const int tid  = threadIdx.x;
    const int wave = tid >> 6;
    const int lane = tid & 63;
    const int quad = lane >> 4;
    const int l16  = lane & 15;

    const int row0 = blockIdx.x * 128;
    const int col0 = blockIdx.y * 128;
    const int z    = blockIdx.z;
    const int Kh   = K >> 1;

    const unsigned short* Az  = A  + (size_t)z * Kh;
    const unsigned short* Btz = Bt + (size_t)z * Kh;
    float* out = z ? out1 : out0;

    const int ldrow = lane >> 2;
    const int ldk   = (lane & 3) * 8;
    const unsigned short* agp0 = Az  + (size_t)(row0 + wave * 32 + ldrow) * K + ldk;
    const unsigned short* agp1 = agp0 + (size_t)16 * K;
    const unsigned short* bgp0 = Btz + (size_t)(col0 + wave * 32 + ldrow) * K + ldk;
    const unsigned short* bgp1 = bgp0 + (size_t)16 * K;
    LDS_AS void* alds0 = (LDS_AS void*)&As[wave * 1024 + lane * 8];
    LDS_AS void* alds1 = (LDS_AS void*)&As[wave * 1024 + 512 + lane * 8];
    LDS_AS void* blds0 = (LDS_AS void*)&Bs[wave * 1024 + lane * 8];
    LDS_AS void* blds1 = (LDS_AS void*)&Bs[wave * 1024 + 512 + lane * 8];

    const int wm = (wave >> 1) * 64;
    const int wn = (wave & 1) * 64;

    f32x4 acc[4][4] = {};

    for (int k0 = 0; k0 < Kh; k0 += 32) {
        __builtin_amdgcn_global_load_lds(
            (const GLOBAL_AS void*)(agp0 + k0), alds0, 16, 0, 0);
        __builtin_amdgcn_global_load_lds(
            (const GLOBAL_AS void*)(agp1 + k0), alds1, 16, 0, 0);
        __builtin_amdgcn_global_load_lds(
            (const GLOBAL_AS void*)(bgp0 + k0), blds0, 16, 0, 0);
        __builtin_amdgcn_global_load_lds(
            (const GLOBAL_AS void*)(bgp1 + k0), blds1, 16, 0, 0);
        __syncthreads();

        bf16x8 af[4], bfr[4];
#pragma unroll
        for (int mi = 0; mi < 4; mi++)
            af[mi] = *reinterpret_cast<const bf16x8*>(
                &As[(wm + mi * 16 + l16) * 32 + quad * 8]);
#pragma unroll
        for (int ni = 0; ni < 4; ni++)
            bfr[ni] = *reinterpret_cast<const bf16x8*>(
                &Bs[(wn + ni * 16 + l16) * 32 + quad * 8]);
#pragma unroll
        for (int mi = 0; mi < 4; mi++)
#pragma unroll
            for (int ni = 0; ni < 4; ni++)
                acc[mi][ni] = __builtin_amdgcn_mfma_f32_16x16x32_bf16(
                    af[mi], bfr[ni], acc[mi][ni], 0, 0, 0);
        __syncthreads();
    }

#pragma unroll
    for (int ni = 0; ni < 4; ni++) {
        const int col = col0 + wn + ni * 16 + l16;
#pragma unroll
        for (int mi = 0; mi < 4; mi++)
#pragma unroll
            for (int r = 0; r < 4; r++) {
                const int row = row0 + wm + mi * 16 + quad * 4 + r;
                out[(size_t)row * N + col] = acc[mi][ni][r];
            }
    }
}

// ---------------------------------------------------------------------------
// Flash attention v6: key-PERMUTED P/V (pi(key) = (key&15)*4 + (key>>4)).
// PV is permutation-invariant in k, so applying pi to BOTH Ps and Vt lets a
// softmax lane write its 4 p-values (keys {l16,16+l16,32+l16,48+l16} ->
// pos 4*l16..4*l16+3) as ONE packed ds_write_b64 (was 4 ds_write_b16), and
// Ps reads become straight b128 (no rotation). V staging pairs keys (k,k+16)
// (adjacent pos) packed b32, pos-oct XOR soct to spread banks. Ks/QK path,
// reg-prefetch pipeline, pre-scaled Q, no-max softmax all unchanged.
// ---------------------------------------------------------------------------
__global__ __launch_bounds__(256) void attn_kernel(
    const unsigned short* __restrict__ qkv,
    unsigned short* __restrict__ ao)
{
    const int qt = blockIdx.x;
    const int h  = blockIdx.y;
    const int b  = blockIdx.z;

    const int tid  = threadIdx.x;
    const int wave = tid >> 6;
    const int lane = tid & 63;
    const int quad = lane >> 4;
    const int l16  = lane & 15;

    __shared__ short Ks[64 * 72];       // [key][dim], octet-swizzled
    __shared__ short Vt[64 * 72];       // [dim][pos], pos-oct ^ (d>>3)
    __shared__ short Ps[4 * 32 * 72];   // per-wave [m][pos]

    bf16x8 qf[2][2];
#pragma unroll
    for (int mi = 0; mi < 2; mi++) {
        const int qrow = qt * 128 + wave * 32 + mi * 16 + l16;
        const unsigned short* qb = qkv + (size_t)(b * S_ + qrow) * 3072 + h * 192;
        qf[mi][0] = *reinterpret_cast<const bf16x8*>(qb + quad * 8);
        qf[mi][1] = *reinterpret_cast<const bf16x8*>(qb + 32 + quad * 8);
    }

    f32x4 o[2][4] = {};
    float l_[2][4] = {};

    // staging indices
    const int skey = tid >> 3;        // 0..31 (K rows)
    const int soct = tid & 7;         // 0..7  (dim octet)
    const int vp   = tid >> 3;        // 0..31 (V key pair id)
    const int kA   = (vp & 15) + ((vp >> 4) << 5);   // keys 0..15, 32..47
    const int kB   = kA + 16;                         // keys 16..31, 48..63
    const int posA = 4 * (vp & 15) + 2 * (vp >> 4);   // pi(kA); pi(kB)=posA+1
    const int vwr  = ((posA >> 3) ^ soct) * 8 + (posA & 7);  // within-row shorts

    const int pb = wave * (32 * 72);  // Ps wave base (shorts)

    const unsigned short* kbase0 = qkv + (size_t)(b * S_) * 3072 + h * 192 + 64;
    const unsigned short* vbase0 = qkv + (size_t)(b * S_) * 3072 + h * 192 + 128;

    // prefetch tile 0
    bf16x8 pk0 = *reinterpret_cast<const bf16x8*>(kbase0 + (size_t)skey * 3072 + soct * 8);
    bf16x8 pk1 = *reinterpret_cast<const bf16x8*>(kbase0 + (size_t)(skey + 32) * 3072 + soct * 8);
    bf16x8 pv0 = *reinterpret_cast<const bf16x8*>(vbase0 + (size_t)kA * 3072 + soct * 8);
    bf16x8 pv1 = *reinterpret_cast<const bf16x8*>(vbase0 + (size_t)kB * 3072 + soct * 8);

    for (int kb = 0; kb < S_; kb += 64) {
        // --- write prefetched tile to LDS ---
        {
            const int woct0 = soct ^ ((skey >> 3) & 1);
            *reinterpret_cast<bf16x8*>(&Ks[skey * 72 + woct0 * 8]) = pk0;
            const int woct1 = soct ^ (((skey + 32) >> 3) & 1);
            *reinterpret_cast<bf16x8*>(&Ks[(skey + 32) * 72 + woct1 * 8]) = pk1;
#pragma unroll
            for (int j = 0; j < 8; j++) {
                const int d = soct * 8 + j;
                const unsigned int val =
                    (unsigned int)(unsigned short)pv0[j] |
                    ((unsigned int)(unsigned short)pv1[j] << 16);
                *reinterpret_cast<unsigned int*>(&Vt[d * 72 + vwr]) = val;
            }
        }
        __syncthreads();

        // --- issue next tile's global loads ---
        {
            const int kbn = (kb + 64 < S_) ? kb + 64 : kb;
            pk0 = *reinterpret_cast<const bf16x8*>(
                kbase0 + (size_t)(kbn + skey) * 3072 + soct * 8);
            pk1 = *reinterpret_cast<const bf16x8*>(
                kbase0 + (size_t)(kbn + skey + 32) * 3072 + soct * 8);
            pv0 = *reinterpret_cast<const bf16x8*>(
                vbase0 + (size_t)(kbn + kA) * 3072 + soct * 8);
            pv1 = *reinterpret_cast<const bf16x8*>(
                vbase0 + (size_t)(kbn + kB) * 3072 + soct * 8);
        }

        // --- QK^T (Q pre-scaled by KLOG2E) ---
        f32x4 s[2][4] = {};
#pragma unroll
        for (int c2 = 0; c2 < 2; c2++) {
#pragma unroll
            for (int nt = 0; nt < 4; nt++) {
                const int key = nt * 16 + l16;
                const int roct = (c2 * 4 + quad) ^ ((key >> 3) & 1);
                bf16x8 kf = *reinterpret_cast<const bf16x8*>(
                    &Ks[key * 72 + roct * 8]);
                s[0][nt] = __builtin_amdgcn_mfma_f32_16x16x32_bf16(qf[0][c2], kf, s[0][nt], 0, 0, 0);
                s[1][nt] = __builtin_amdgcn_mfma_f32_16x16x32_bf16(qf[1][c2], kf, s[1][nt], 0, 0, 0);
            }
        }

        // --- no-max softmax: p = 2^s; packed b64 P-store at pos 4*l16 ---
#pragma unroll
        for (int mi = 0; mi < 2; mi++) {
#pragma unroll
            for (int r = 0; r < 4; r++) {
                const int m = mi * 16 + quad * 4 + r;
                float p0 = exp2f(s[mi][0][r]);
                float p1 = exp2f(s[mi][1][r]);
                float p2 = exp2f(s[mi][2][r]);
                float p3 = exp2f(s[mi][3][r]);
                l_[mi][r] += (p0 + p1) + (p2 + p3);
                uint2 w;
                w.x = (unsigned int)(unsigned short)f2bf(p0) |
                      ((unsigned int)(unsigned short)f2bf(p1) << 16);
                w.y = (unsigned int)(unsigned short)f2bf(p2) |
                      ((unsigned int)(unsigned short)f2bf(p3) << 16);
                *reinterpret_cast<uint2*>(&Ps[pb + m * 72 + l16 * 4]) = w;
            }
        }
        // (Ps is wave-private: in-wave RAW handled by waitcnt, no barrier)

        // --- PV in pos-space: A = Ps straight b128, B = Vt (oct ^ d>>3) ---
#pragma unroll
        for (int c2 = 0; c2 < 2; c2++) {
            bf16x8 pf[2];
#pragma unroll
            for (int mi = 0; mi < 2; mi++) {
                const int m = mi * 16 + l16;
                pf[mi] = *reinterpret_cast<const bf16x8*>(
                    &Ps[pb + m * 72 + c2 * 32 + quad * 8]);
            }
#pragma unroll
            for (int ct = 0; ct < 4; ct++) {
                const int row = ct * 16 + l16;
                const int blk = (c2 * 4 + quad) ^ (row >> 3);
                bf16x8 vf = *reinterpret_cast<const bf16x8*>(
                    &Vt[row * 72 + blk * 8]);
                o[0][ct] = __builtin_amdgcn_mfma_f32_16x16x32_bf16(pf[0], vf, o[0][ct], 0, 0, 0);
                o[1][ct] = __builtin_amdgcn_mfma_f32_16x16x32_bf16(pf[1], vf, o[1][ct], 0, 0, 0);
            }
        }
        __syncthreads();
    }

    float rl[2][4];
#pragma unroll
    for (int mi = 0; mi < 2; mi++)
#pragma unroll
        for (int r = 0; r < 4; r++) {
            float l = l_[mi][r];
            l += __shfl_xor(l, 1);
            l += __shfl_xor(l, 2);
            l += __shfl_xor(l, 4);
            l += __shfl_xor(l, 8);
            rl[mi][r] = 1.f / l;
        }

#pragma unroll
    for (int mi = 0; mi < 2; mi++)
#pragma unroll
        for (int ct = 0; ct < 4; ct++)
#pragma unroll
            for (int r = 0; r < 4; r++) {
                const int row = qt * 128 + wave * 32 + mi * 16 + quad * 4 + r;
                ao[(size_t)(b * S_ + row) * D_ + h * HD_ + ct * 16 + l16] =
                    (unsigned short)f2bf(o[mi][ct][r] * rl[mi][r]);
            }
}

// ---------------------------------------------------------------------------
// LN over D=1024 with fused partial-sum + bias + residual.
// ---------------------------------------------------------------------------
template<int RESM, bool FLAG_OUT>
__global__ __launch_bounds__(256) void ln_sum_kernel(
    const float* __restrict__ p0,
    const float* __restrict__ p1,
    const float* __restrict__ bias,
    const unsigned short* __restrict__ resb,
    const float* __restrict__ resf,
    const float* __restrict__ g,
    const float* __restrict__ bt,
    const int* __restrict__ flags,
    void* __restrict__ out)
{
    const int row = blockIdx.x;
    const int tid = threadIdx.x;
    const int c0  = tid * 4;
    const size_t base = (size_t)row * D_ + c0;

    float4 a = *reinterpret_cast<const float4*>(p0 + base);
    float4 bq = *reinterpret_cast<const float4*>(p1 + base);
    float4 bi = *reinterpret_cast<const float4*>(bias + c0);

    float v[4] = {a.x + bq.x + bi.x, a.y + bq.y + bi.y,
                  a.z + bq.z + bi.z, a.w + bq.w + bi.w};

    if constexpr (RESM == 1) {
        if (flags[0]) {
            float4 rv = *reinterpret_cast<const float4*>(resf + base);
            v[0] += rv.x; v[1] += rv.y; v[2] += rv.z; v[3] += rv.w;
        } else {
            uint2 rv = *reinterpret_cast<const uint2*>(resb + base);
            v[0] += bf2f((unsigned short)(rv.x & 0xFFFF));
            v[1] += bf2f((unsigned short)(rv.x >> 16));
            v[2] += bf2f((unsigned short)(rv.y & 0xFFFF));
            v[3] += bf2f((unsigned short)(rv.y >> 16));
        }
    } else {
        uint2 rv = *reinterpret_cast<const uint2*>(resb + base);
        v[0] += bf2f((unsigned short)(rv.x & 0xFFFF));
        v[1] += bf2f((unsigned short)(rv.x >> 16));
        v[2] += bf2f((unsigned short)(rv.y & 0xFFFF));
        v[3] += bf2f((unsigned short)(rv.y >> 16));
    }

    float s = v[0] + v[1] + v[2] + v[3];
    float sq = v[0] * v[0] + v[1] * v[1] + v[2] * v[2] + v[3] * v[3];
#pragma unroll
    for (int msk = 1; msk < 64; msk <<= 1) {
        s += __shfl_xor(s, msk);
        sq += __shfl_xor(sq, msk);
    }
    __shared__ float ss[4], ssq[4];
    if ((tid & 63) == 0) { ss[tid >> 6] = s; ssq[tid >> 6] = sq; }
    __syncthreads();
    s = ss[0] + ss[1] + ss[2] + ss[3];
    sq = ssq[0] + ssq[1] + ssq[2] + ssq[3];

    const float mean = s * (1.f / D_);
    const float var = sq * (1.f / D_) - mean * mean;
    const float rinv = rsqrtf(var + EPS_);

    int outF32 = 0;
    if constexpr (FLAG_OUT) outF32 = flags[0];

#pragma unroll
    for (int i = 0; i < 4; i++) {
        const int c = c0 + i;
        const float val = (v[i] - mean) * rinv * g[c] + bt[c];
        if constexpr (FLAG_OUT) {
            if (outF32) ((float*)out)[(size_t)row * D_ + c] = val;
            else ((unsigned short*)out)[(size_t)row * D_ + c] = (unsigned short)f2bf(val);
        } else {
            ((unsigned short*)out)[(size_t)row * D_ + c] = (unsigned short)f2bf(val);
        }
    }
}

// ---------------------------------------------------------------------------
extern "C" void kernel_launch(void* const* d_in, const int* in_sizes, int n_in,
                              void* d_out, int out_size, void* d_ws, size_t ws_size,
                              hipStream_t stream) {
    char* ws = (char*)d_ws;

    int*            flags = (int*)(ws + 0);
    unsigned short* xb    = (unsigned short*)(ws + 256);
    unsigned short* wqkvT = (unsigned short*)(ws + 8388864);
    unsigned short* woT   = (unsigned short*)(ws + 14680320);
    unsigned short* w1T   = (unsigned short*)(ws + 16777472);
    unsigned short* w2T   = (unsigned short*)(ws + 25166080);
    float*          bof   = (float*)(ws + 33554688);
    float*          g1f   = (float*)(ws + 33558784);
    float*          bt1f  = (float*)(ws + 33562880);
    float*          b1f   = (float*)(ws + 33566976);
    float*          b2f   = (float*)(ws + 33583360);
    float*          g2f   = (float*)(ws + 33587456);
    float*          bt2f  = (float*)(ws + 33591552);
    unsigned short* qkv   = (unsigned short*)(ws + 33595648);
    unsigned short* ao    = (unsigned short*)(ws + 256);          // reuse xb
    unsigned short* y     = (unsigned short*)(ws + 33595648);     // reuse qkv
    unsigned short* hbuf  = (unsigned short*)(ws + 41984256);
    float*          part0 = (float*)(ws + 58761472);
    float*          part1 = (float*)(ws + 75538688);
    float*          hpart0= (float*)(ws + 256);                   // reuse ao slot

    dim3 blk(256);

    DetectArgs da;
    for (int i = 0; i < 12; i++) {
        da.p[i] = (const unsigned short*)d_in[i];
        da.n[i] = in_sizes[i];
    }
    detect_kernel<<<dim3(12), blk, 0, stream>>>(da, flags);

    conv_bf16_kernel<<<dim3((NT * D_ + 255) / 256), blk, 0, stream>>>(
        d_in[0], xb, NT * D_, flags, 0);
    conv_t_kernel<<<dim3(D_ / 32, 3 * D_ / 32), blk, 0, stream>>>(
        d_in[1], wqkvT, D_, 3 * D_, flags, 1);
    conv_t_kernel<<<dim3(D_ / 32, D_ / 32), blk, 0, stream>>>(
        d_in[2], woT, D_, D_, flags, 2);
    conv_t_kernel<<<dim3(D_ / 32, FF_ / 32), blk, 0, stream>>>(
        d_in[6], w1T, D_, FF_, flags, 6);
    conv_t_kernel<<<dim3(FF_ / 32, D_ / 32), blk, 0, stream>>>(
        d_in[8], w2T, FF_, D_, flags, 8);
    VecArgs va;
    const int vidx[7] = {3, 4, 5, 7, 9, 10, 11};
    float* vdst[7] = {bof, g1f, bt1f, b1f, b2f, g2f, bt2f};
    for (int i = 0; i < 7; i++) {
        va.src[i] = d_in[vidx[i]];
        va.dst[i] = vdst[i];
        va.n[i]   = in_sizes[vidx[i]];
        va.fidx[i] = vidx[i];
    }
    conv_vecs_kernel<<<dim3(16), blk, 0, stream>>>(va, flags);

    // 1) qkv = x @ w_qkv, Q part pre-scaled by KLOG2E
    gemm128_kernel<false, false, 0, false, true>
        <<<dim3(NT / 128, 3072 / 128), blk, 0, stream>>>(
            xb, wqkvT, nullptr, nullptr, nullptr, flags, qkv, NT, 3072, 1024);

    // 2) attention -> ao bf16
    attn_kernel<<<dim3(S_ / 128, H_, B_), blk, 0, stream>>>(qkv, ao);

    // 3) wo projection, split-K x2 -> raw f32 partials
    gemm128_sk_kernel<<<dim3(NT / 128, 1024 / 128, 2), blk, 0, stream>>>(
        ao, woT, part0, part1, NT, 1024, 1024);

    // 4) y = LN(part0+part1 + b_o + x)
    ln_sum_kernel<1, false><<<dim3(NT), blk, 0, stream>>>(
        part0, part1, bof, (const unsigned short*)d_in[0], (const float*)d_in[0],
        g1f, bt1f, flags, y);

    // 5) h = relu(y @ w1 + b1)
    gemm128_kernel<true, true, 0, false, false>
        <<<dim3(NT / 128, 4096 / 128), blk, 0, stream>>>(
            y, w1T, b1f, nullptr, nullptr, flags, hbuf, NT, 4096, 1024);

    // 6) FFN2, split-K x2 -> raw f32 partials
    gemm128_sk_kernel<<<dim3(NT / 128, 1024 / 128, 2), blk, 0, stream>>>(
        hbuf, w2T, hpart0, part1, NT, 1024, 4096);

    // 7) out = LN(hpart0+part1 + b2 + y), output dtype per flags[0]
    ln_sum_kernel<2, true><<<dim3(NT), blk, 0, stream>>>(
        hpart0, part1, b2f, y, nullptr, g2f, bt2f, flags, d_out);
}

// Round 10
// 391.973 us; speedup vs baseline: 1.1220x; 1.1220x over previous
//
#include <hip/hip_runtime.h>
#include <hip/hip_bf16.h>

// Shapes (fixed by the problem)
#define B_  2
#define S_  2048
#define D_  1024
#define H_  16
#define HD_ 64
#define FF_ 4096
#define NT  (B_ * S_)          // 4096 tokens
#define SCALE_ 0.125f          // 1/sqrt(64)
#define KLOG2E 0.1803368801111f // SCALE * log2(e)
#define EPS_  1e-5f

typedef __attribute__((ext_vector_type(8))) short bf16x8;   // 8 bf16 = 4 VGPRs
typedef __attribute__((ext_vector_type(4))) float f32x4;    // MFMA C/D frag

__device__ inline short f2bf(float f) {
    __hip_bfloat16 h = __float2bfloat16(f);
    return __builtin_bit_cast(short, h);
}
__device__ inline float bf2f(unsigned short u) {
    __hip_bfloat16 h = __builtin_bit_cast(__hip_bfloat16, u);
    return __bfloat162float(h);
}
// packed f32x2 -> bf16x2 (v_cvt_pk_bf16_f32 on gfx950), lo in low 16 bits.
// NOTE: __hip_bfloat162 is NOT trivially copyable -> bit-cast members.
__device__ inline unsigned int pk2bf(float lo, float hi) {
    __hip_bfloat162 h = __float22bfloat162_rn(float2{lo, hi});
    const unsigned short l16 = __builtin_bit_cast(unsigned short, h.x);
    const unsigned short h16 = __builtin_bit_cast(unsigned short, h.y);
    return (unsigned int)l16 | ((unsigned int)h16 << 16);
}

#define GLOBAL_AS __attribute__((address_space(1)))
#define LDS_AS    __attribute__((address_space(3)))

// ---------------------------------------------------------------------------
// Dtype detection (verified working)
// ---------------------------------------------------------------------------
struct DetectArgs { const unsigned short* p[12]; int n[12]; };

__global__ __launch_bounds__(256) void detect_kernel(DetectArgs a, int* flags) {
    const int t = blockIdx.x;
    const unsigned short* s = a.p[t];
    const int cnt = min(a.n[t], 16384);
    const int tid = threadIdx.x;
    int huge = 0, zeven = 0;
    for (int i = tid; i < cnt; i += 256) {
        const unsigned short v = s[i];
        const int e = (v >> 7) & 0xFF;
        if (e >= 142) huge++;
        if (((i & 1) == 0) && ((v & 0x7FFF) == 0)) zeven++;
    }
    __shared__ int sh, sz;
    if (tid == 0) { sh = 0; sz = 0; }
    __syncthreads();
    atomicAdd(&sh, huge);
    atomicAdd(&sz, zeven);
    __syncthreads();
    if (tid == 0) flags[t] = (sh > 0 || sz * 4 > cnt) ? 1 : 0;
}

// x convert -> bf16; block 0..6 also convert the 7 small f32 vectors
struct VecArgs { const void* src[7]; float* dst[7]; int n[7]; int fidx[7]; };

__global__ __launch_bounds__(256) void conv_x_vecs_kernel(
    const void* __restrict__ src, unsigned short* __restrict__ dst, int n,
    VecArgs a, const int* __restrict__ flags)
{
    const int i = blockIdx.x * 256 + threadIdx.x;
    if (i < n) {
        if (flags[0])
            dst[i] = (unsigned short)f2bf(((const float*)src)[i]);
        else
            dst[i] = ((const unsigned short*)src)[i];
    }
    if (blockIdx.x < 7) {
        const int v = blockIdx.x;
        const int f = flags[a.fidx[v]];
        for (int j = threadIdx.x; j < a.n[v]; j += 256) {
            a.dst[v][j] = f ? ((const float*)a.src[v])[j]
                            : bf2f(((const unsigned short*)a.src[v])[j]);
        }
    }
}

// fused tiled transpose convert for all 4 weights: src [K,N] -> dst [N,K] bf16
struct TArgs {
    const void* src[4]; unsigned short* dst[4];
    int K[4], N[4], fidx[4], start[5];
};

__global__ __launch_bounds__(256) void conv_t_all_kernel(
    TArgs t, const int* __restrict__ flags)
{
    __shared__ short T[32][33];
    const int tile = blockIdx.x;
    int w = 0;
    if (tile >= t.start[1]) w = 1;
    if (tile >= t.start[2]) w = 2;
    if (tile >= t.start[3]) w = 3;
    const int rel = tile - t.start[w];
    const int K = t.K[w], N = t.N[w];
    const int tilesN = N / 32;
    const int kt = (rel / tilesN) * 32, nt = (rel % tilesN) * 32;
    const void* src = t.src[w];
    unsigned short* dst = t.dst[w];
    const int f = flags[t.fidx[w]];

    const int c  = threadIdx.x & 31;
    const int r0 = (threadIdx.x >> 5) * 4;
#pragma unroll
    for (int i = 0; i < 4; i++) {
        const int r = r0 + i;
        const size_t gi = (size_t)(kt + r) * N + nt + c;
        short v = f ? f2bf(((const float*)src)[gi])
                    : (short)((const unsigned short*)src)[gi];
        T[c][r] = v;
    }
    __syncthreads();
#pragma unroll
    for (int i = 0; i < 4; i++) {
        const int n = r0 + i;
        dst[(size_t)(nt + n) * K + kt + c] = (unsigned short)T[n][c];
    }
}

// ---------------------------------------------------------------------------
// 128x128 MFMA GEMM, BK=64 = two verified BK=32 sub-stages per barrier pair
// (halves barrier count vs m97; LDS 32 KB; stride-32 layout unchanged).
// QSCALE: scale Q-part cols of the qkv projection by KLOG2E.
// ---------------------------------------------------------------------------
template<bool HAS_BIAS, bool RELU, int RES, bool OUT_F32, bool QSCALE>
__global__ __launch_bounds__(256) void gemm128_kernel(
    const unsigned short* __restrict__ A,
    const unsigned short* __restrict__ Bt,
    const float* __restrict__ bias,
    const unsigned short* __restrict__ resb,
    const float* __restrict__ resf,
    const int* __restrict__ flags,
    void* __restrict__ out,
    int M, int N, int K)
{
    __shared__ short As[2][128 * 32];
    __shared__ short Bs[2][128 * 32];

    const int tid  = threadIdx.x;
    const int wave = tid >> 6;
    const int lane = tid & 63;
    const int quad = lane >> 4;
    const int l16  = lane & 15;

    const int row0 = blockIdx.x * 128;
    const int col0 = blockIdx.y * 128;

    const int ldrow = lane >> 2;
    const int ldk   = (lane & 3) * 8;
    const unsigned short* agp0 = A  + (size_t)(row0 + wave * 32 + ldrow) * K + ldk;
    const unsigned short* agp1 = agp0 + (size_t)16 * K;
    const unsigned short* bgp0 = Bt + (size_t)(col0 + wave * 32 + ldrow) * K + ldk;
    const unsigned short* bgp1 = bgp0 + (size_t)16 * K;

    const int wm = (wave >> 1) * 64;
    const int wn = (wave & 1) * 64;

    f32x4 acc[4][4] = {};

    for (int k0 = 0; k0 < K; k0 += 64) {
#pragma unroll
        for (int h = 0; h < 2; h++) {
            __builtin_amdgcn_global_load_lds(
                (const GLOBAL_AS void*)(agp0 + k0 + h * 32),
                (LDS_AS void*)&As[h][wave * 1024 + lane * 8], 16, 0, 0);
            __builtin_amdgcn_global_load_lds(
                (const GLOBAL_AS void*)(agp1 + k0 + h * 32),
                (LDS_AS void*)&As[h][wave * 1024 + 512 + lane * 8], 16, 0, 0);
            __builtin_amdgcn_global_load_lds(
                (const GLOBAL_AS void*)(bgp0 + k0 + h * 32),
                (LDS_AS void*)&Bs[h][wave * 1024 + lane * 8], 16, 0, 0);
            __builtin_amdgcn_global_load_lds(
                (const GLOBAL_AS void*)(bgp1 + k0 + h * 32),
                (LDS_AS void*)&Bs[h][wave * 1024 + 512 + lane * 8], 16, 0, 0);
        }
        __syncthreads();

#pragma unroll
        for (int h = 0; h < 2; h++) {
            bf16x8 af[4], bfr[4];
#pragma unroll
            for (int mi = 0; mi < 4; mi++)
                af[mi] = *reinterpret_cast<const bf16x8*>(
                    &As[h][(wm + mi * 16 + l16) * 32 + quad * 8]);
#pragma unroll
            for (int ni = 0; ni < 4; ni++)
                bfr[ni] = *reinterpret_cast<const bf16x8*>(
                    &Bs[h][(wn + ni * 16 + l16) * 32 + quad * 8]);
#pragma unroll
            for (int mi = 0; mi < 4; mi++)
#pragma unroll
                for (int ni = 0; ni < 4; ni++)
                    acc[mi][ni] = __builtin_amdgcn_mfma_f32_16x16x32_bf16(
                        af[mi], bfr[ni], acc[mi][ni], 0, 0, 0);
        }
        __syncthreads();
    }

    int resIsF32 = 0;
    if constexpr (RES == 2) resIsF32 = flags[0];

#pragma unroll
    for (int ni = 0; ni < 4; ni++) {
        const int col = col0 + wn + ni * 16 + l16;
        float badd = 0.f;
        if constexpr (HAS_BIAS) badd = bias[col];
        float qs = 1.f;
        if constexpr (QSCALE)
            qs = (((col0 + wn + ni * 16) % 192) < 64) ? KLOG2E : 1.f;
#pragma unroll
        for (int mi = 0; mi < 4; mi++) {
#pragma unroll
            for (int r = 0; r < 4; r++) {
                const int row = row0 + wm + mi * 16 + quad * 4 + r;
                float v = acc[mi][ni][r] + badd;
                if constexpr (QSCALE) v *= qs;
                if constexpr (RES == 1) {
                    v += bf2f(resb[(size_t)row * N + col]);
                } else if constexpr (RES == 2) {
                    v += resIsF32 ? resf[(size_t)row * N + col]
                                  : bf2f(resb[(size_t)row * N + col]);
                }
                if constexpr (RELU) v = fmaxf(v, 0.f);
                if constexpr (OUT_F32)
                    ((float*)out)[(size_t)row * N + col] = v;
                else
                    ((unsigned short*)out)[(size_t)row * N + col] =
                        (unsigned short)f2bf(v);
            }
        }
    }
}

// ---------------------------------------------------------------------------
// Split-K 128x128 GEMM, BK=64 two-stage; raw f32 partials.
// ---------------------------------------------------------------------------
__global__ __launch_bounds__(256) void gemm128_sk_kernel(
    const unsigned short* __restrict__ A,
    const unsigned short* __restrict__ Bt,
    float* __restrict__ out0,
    float* __restrict__ out1,
    int M, int N, int K)
{
    __shared__ short As[2][128 * 32];
    __shared__ short Bs[2][128 * 32];

    const int tid  = threadIdx.x;
    const int wave = tid >> 6;
    const int lane = tid & 63;
    const int quad = lane >> 4;
    const int l16  = lane & 15;

    const int row0 = blockIdx.x * 128;
    const int col0 = blockIdx.y * 128;
    const int z    = blockIdx.z;
    const int Kh   = K >> 1;

    const unsigned short* Az  = A  + (size_t)z * Kh;
    const unsigned short* Btz = Bt + (size_t)z * Kh;
    float* out = z ? out1 : out0;

    const int ldrow = lane >> 2;
    const int ldk   = (lane & 3) * 8;
    const unsigned short* agp0 = Az  + (size_t)(row0 + wave * 32 + ldrow) * K + ldk;
    const unsigned short* agp1 = agp0 + (size_t)16 * K;
    const unsigned short* bgp0 = Btz + (size_t)(col0 + wave * 32 + ldrow) * K + ldk;
    const unsigned short* bgp1 = bgp0 + (size_t)16 * K;

    const int wm = (wave >> 1) * 64;
    const int wn = (wave & 1) * 64;

    f32x4 acc[4][4] = {};

    for (int k0 = 0; k0 < Kh; k0 += 64) {
#pragma unroll
        for (int h = 0; h < 2; h++) {
            __builtin_amdgcn_global_load_lds(
                (const GLOBAL_AS void*)(agp0 + k0 + h * 32),
                (LDS_AS void*)&As[h][wave * 1024 + lane * 8], 16, 0, 0);
            __builtin_amdgcn_global_load_lds(
                (const GLOBAL_AS void*)(agp1 + k0 + h * 32),
                (LDS_AS void*)&As[h][wave * 1024 + 512 + lane * 8], 16, 0, 0);
            __builtin_amdgcn_global_load_lds(
                (const GLOBAL_AS void*)(bgp0 + k0 + h * 32),
                (LDS_AS void*)&Bs[h][wave * 1024 + lane * 8], 16, 0, 0);
            __builtin_amdgcn_global_load_lds(
                (const GLOBAL_AS void*)(bgp1 + k0 + h * 32),
                (LDS_AS void*)&Bs[h][wave * 1024 + 512 + lane * 8], 16, 0, 0);
        }
        __syncthreads();

#pragma unroll
        for (int h = 0; h < 2; h++) {
            bf16x8 af[4], bfr[4];
#pragma unroll
            for (int mi = 0; mi < 4; mi++)
                af[mi] = *reinterpret_cast<const bf16x8*>(
                    &As[h][(wm + mi * 16 + l16) * 32 + quad * 8]);
#pragma unroll
            for (int ni = 0; ni < 4; ni++)
                bfr[ni] = *reinterpret_cast<const bf16x8*>(
                    &Bs[h][(wn + ni * 16 + l16) * 32 + quad * 8]);
#pragma unroll
            for (int mi = 0; mi < 4; mi++)
#pragma unroll
                for (int ni = 0; ni < 4; ni++)
                    acc[mi][ni] = __builtin_amdgcn_mfma_f32_16x16x32_bf16(
                        af[mi], bfr[ni], acc[mi][ni], 0, 0, 0);
        }
        __syncthreads();
    }

#pragma unroll
    for (int ni = 0; ni < 4; ni++) {
        const int col = col0 + wn + ni * 16 + l16;
#pragma unroll
        for (int mi = 0; mi < 4; mi++)
#pragma unroll
            for (int r = 0; r < 4; r++) {
                const int row = row0 + wm + mi * 16 + quad * 4 + r;
                out[(size_t)row * N + col] = acc[mi][ni][r];
            }
    }
}

// ---------------------------------------------------------------------------
// Flash attention v7: key-permuted P/V, b64 P-store, reg prefetch, pre-scaled
// Q, l via all-ones-B MFMA, packed v_cvt_pk_bf16_f32 P-store.
// ---------------------------------------------------------------------------
__global__ __launch_bounds__(256) void attn_kernel(
    const unsigned short* __restrict__ qkv,
    unsigned short* __restrict__ ao)
{
    const int qt = blockIdx.x;
    const int h  = blockIdx.y;
    const int b  = blockIdx.z;

    const int tid  = threadIdx.x;
    const int wave = tid >> 6;
    const int lane = tid & 63;
    const int quad = lane >> 4;
    const int l16  = lane & 15;

    __shared__ short Ks[64 * 72];       // [key][dim], octet-swizzled
    __shared__ short Vt[64 * 72];       // [dim][pos], pos-oct ^ (d>>3)
    __shared__ short Ps[4 * 32 * 72];   // per-wave [m][pos]

    bf16x8 qf[2][2];
#pragma unroll
    for (int mi = 0; mi < 2; mi++) {
        const int qrow = qt * 128 + wave * 32 + mi * 16 + l16;
        const unsigned short* qb = qkv + (size_t)(b * S_ + qrow) * 3072 + h * 192;
        qf[mi][0] = *reinterpret_cast<const bf16x8*>(qb + quad * 8);
        qf[mi][1] = *reinterpret_cast<const bf16x8*>(qb + 32 + quad * 8);
    }

    // all-ones B fragment for the l row-sum MFMA
    bf16x8 vones;
#pragma unroll
    for (int j = 0; j < 8; j++) vones[j] = (short)0x3F80;

    f32x4 o[2][4] = {};
    f32x4 o_l[2] = {};                // l accumulator (row sums of P)

    const int skey = tid >> 3;        // 0..31 (K rows)
    const int soct = tid & 7;         // 0..7  (dim octet)
    const int vp   = tid >> 3;        // 0..31 (V key pair id)
    const int kA   = (vp & 15) + ((vp >> 4) << 5);
    const int kB   = kA + 16;
    const int posA = 4 * (vp & 15) + 2 * (vp >> 4);
    const int vwr  = ((posA >> 3) ^ soct) * 8 + (posA & 7);

    const int pb = wave * (32 * 72);

    const unsigned short* kbase0 = qkv + (size_t)(b * S_) * 3072 + h * 192 + 64;
    const unsigned short* vbase0 = qkv + (size_t)(b * S_) * 3072 + h * 192 + 128;

    bf16x8 pk0 = *reinterpret_cast<const bf16x8*>(kbase0 + (size_t)skey * 3072 + soct * 8);
    bf16x8 pk1 = *reinterpret_cast<const bf16x8*>(kbase0 + (size_t)(skey + 32) * 3072 + soct * 8);
    bf16x8 pv0 = *reinterpret_cast<const bf16x8*>(vbase0 + (size_t)kA * 3072 + soct * 8);
    bf16x8 pv1 = *reinterpret_cast<const bf16x8*>(vbase0 + (size_t)kB * 3072 + soct * 8);

    for (int kb = 0; kb < S_; kb += 64) {
        {
            const int woct0 = soct ^ ((skey >> 3) & 1);
            *reinterpret_cast<bf16x8*>(&Ks[skey * 72 + woct0 * 8]) = pk0;
            const int woct1 = soct ^ (((skey + 32) >> 3) & 1);
            *reinterpret_cast<bf16x8*>(&Ks[(skey + 32) * 72 + woct1 * 8]) = pk1;
#pragma unroll
            for (int j = 0; j < 8; j++) {
                const int d = soct * 8 + j;
                const unsigned int val =
                    (unsigned int)(unsigned short)pv0[j] |
                    ((unsigned int)(unsigned short)pv1[j] << 16);
                *reinterpret_cast<unsigned int*>(&Vt[d * 72 + vwr]) = val;
            }
        }
        __syncthreads();

        {
            const int kbn = (kb + 64 < S_) ? kb + 64 : kb;
            pk0 = *reinterpret_cast<const bf16x8*>(
                kbase0 + (size_t)(kbn + skey) * 3072 + soct * 8);
            pk1 = *reinterpret_cast<const bf16x8*>(
                kbase0 + (size_t)(kbn + skey + 32) * 3072 + soct * 8);
            pv0 = *reinterpret_cast<const bf16x8*>(
                vbase0 + (size_t)(kbn + kA) * 3072 + soct * 8);
            pv1 = *reinterpret_cast<const bf16x8*>(
                vbase0 + (size_t)(kbn + kB) * 3072 + soct * 8);
        }

        // --- QK^T ---
        f32x4 s[2][4] = {};
#pragma unroll
        for (int c2 = 0; c2 < 2; c2++) {
#pragma unroll
            for (int nt = 0; nt < 4; nt++) {
                const int key = nt * 16 + l16;
                const int roct = (c2 * 4 + quad) ^ ((key >> 3) & 1);
                bf16x8 kf = *reinterpret_cast<const bf16x8*>(
                    &Ks[key * 72 + roct * 8]);
                s[0][nt] = __builtin_amdgcn_mfma_f32_16x16x32_bf16(qf[0][c2], kf, s[0][nt], 0, 0, 0);
                s[1][nt] = __builtin_amdgcn_mfma_f32_16x16x32_bf16(qf[1][c2], kf, s[1][nt], 0, 0, 0);
            }
        }

        // --- softmax: p = 2^s; packed cvt; b64 store at pos 4*l16 ---
#pragma unroll
        for (int mi = 0; mi < 2; mi++) {
#pragma unroll
            for (int r = 0; r < 4; r++) {
                const int m = mi * 16 + quad * 4 + r;
                const float p0 = exp2f(s[mi][0][r]);
                const float p1 = exp2f(s[mi][1][r]);
                const float p2 = exp2f(s[mi][2][r]);
                const float p3 = exp2f(s[mi][3][r]);
                uint2 w;
                w.x = pk2bf(p0, p1);
                w.y = pk2bf(p2, p3);
                *reinterpret_cast<uint2*>(&Ps[pb + m * 72 + l16 * 4]) = w;
            }
        }

        // --- PV + l row-sum via ones MFMA ---
#pragma unroll
        for (int c2 = 0; c2 < 2; c2++) {
            bf16x8 pf[2];
#pragma unroll
            for (int mi = 0; mi < 2; mi++) {
                const int m = mi * 16 + l16;
                pf[mi] = *reinterpret_cast<const bf16x8*>(
                    &Ps[pb + m * 72 + c2 * 32 + quad * 8]);
            }
#pragma unroll
            for (int ct = 0; ct < 4; ct++) {
                const int row = ct * 16 + l16;
                const int blk = (c2 * 4 + quad) ^ (row >> 3);
                bf16x8 vf = *reinterpret_cast<const bf16x8*>(
                    &Vt[row * 72 + blk * 8]);
                o[0][ct] = __builtin_amdgcn_mfma_f32_16x16x32_bf16(pf[0], vf, o[0][ct], 0, 0, 0);
                o[1][ct] = __builtin_amdgcn_mfma_f32_16x16x32_bf16(pf[1], vf, o[1][ct], 0, 0, 0);
            }
            o_l[0] = __builtin_amdgcn_mfma_f32_16x16x32_bf16(pf[0], vones, o_l[0], 0, 0, 0);
            o_l[1] = __builtin_amdgcn_mfma_f32_16x16x32_bf16(pf[1], vones, o_l[1], 0, 0, 0);
        }
        __syncthreads();
    }

    // l is already per-row in o_l[mi][r] (every lane holds it)
#pragma unroll
    for (int mi = 0; mi < 2; mi++) {
        f32x4 rl;
#pragma unroll
        for (int r = 0; r < 4; r++) rl[r] = 1.f / o_l[mi][r];
#pragma unroll
        for (int ct = 0; ct < 4; ct++)
#pragma unroll
            for (int r = 0; r < 4; r++) {
                const int row = qt * 128 + wave * 32 + mi * 16 + quad * 4 + r;
                ao[(size_t)(b * S_ + row) * D_ + h * HD_ + ct * 16 + l16] =
                    (unsigned short)f2bf(o[mi][ct][r] * rl[r]);
            }
    }
}

// ---------------------------------------------------------------------------
// LN over D=1024 with fused partial-sum + bias + residual; packed stores.
// ---------------------------------------------------------------------------
template<int RESM, bool FLAG_OUT>
__global__ __launch_bounds__(256) void ln_sum_kernel(
    const float* __restrict__ p0,
    const float* __restrict__ p1,
    const float* __restrict__ bias,
    const unsigned short* __restrict__ resb,
    const float* __restrict__ resf,
    const float* __restrict__ g,
    const float* __restrict__ bt,
    const int* __restrict__ flags,
    void* __restrict__ out)
{
    const int row = blockIdx.x;
    const int tid = threadIdx.x;
    const int c0  = tid * 4;
    const size_t base = (size_t)row * D_ + c0;

    float4 a = *reinterpret_cast<const float4*>(p0 + base);
    float4 bq = *reinterpret_cast<const float4*>(p1 + base);
    float4 bi = *reinterpret_cast<const float4*>(bias + c0);

    float v[4] = {a.x + bq.x + bi.x, a.y + bq.y + bi.y,
                  a.z + bq.z + bi.z, a.w + bq.w + bi.w};

    if constexpr (RESM == 1) {
        if (flags[0]) {
            float4 rv = *reinterpret_cast<const float4*>(resf + base);
            v[0] += rv.x; v[1] += rv.y; v[2] += rv.z; v[3] += rv.w;
        } else {
            uint2 rv = *reinterpret_cast<const uint2*>(resb + base);
            v[0] += bf2f((unsigned short)(rv.x & 0xFFFF));
            v[1] += bf2f((unsigned short)(rv.x >> 16));
            v[2] += bf2f((unsigned short)(rv.y & 0xFFFF));
            v[3] += bf2f((unsigned short)(rv.y >> 16));
        }
    } else {
        uint2 rv = *reinterpret_cast<const uint2*>(resb + base);
        v[0] += bf2f((unsigned short)(rv.x & 0xFFFF));
        v[1] += bf2f((unsigned short)(rv.x >> 16));
        v[2] += bf2f((unsigned short)(rv.y & 0xFFFF));
        v[3] += bf2f((unsigned short)(rv.y >> 16));
    }

    float s = v[0] + v[1] + v[2] + v[3];
    float sq = v[0] * v[0] + v[1] * v[1] + v[2] * v[2] + v[3] * v[3];
#pragma unroll
    for (int msk = 1; msk < 64; msk <<= 1) {
        s += __shfl_xor(s, msk);
        sq += __shfl_xor(sq, msk);
    }
    __shared__ float ss[4], ssq[4];
    if ((tid & 63) == 0) { ss[tid >> 6] = s; ssq[tid >> 6] = sq; }
    __syncthreads();
    s = ss[0] + ss[1] + ss[2] + ss[3];
    sq = ssq[0] + ssq[1] + ssq[2] + ssq[3];

    const float mean = s * (1.f / D_);
    const float var = sq * (1.f / D_) - mean * mean;
    const float rinv = rsqrtf(var + EPS_);

    float w[4];
#pragma unroll
    for (int i = 0; i < 4; i++)
        w[i] = (v[i] - mean) * rinv * g[c0 + i] + bt[c0 + i];

    int outF32 = 0;
    if constexpr (FLAG_OUT) outF32 = flags[0];

    if (FLAG_OUT && outF32) {
        float4 o4 = {w[0], w[1], w[2], w[3]};
        *reinterpret_cast<float4*>((float*)out + base) = o4;
    } else {
        uint2 o2;
        o2.x = pk2bf(w[0], w[1]);
        o2.y = pk2bf(w[2], w[3]);
        *reinterpret_cast<uint2*>((unsigned short*)out + base) = o2;
    }
}

// ---------------------------------------------------------------------------
extern "C" void kernel_launch(void* const* d_in, const int* in_sizes, int n_in,
                              void* d_out, int out_size, void* d_ws, size_t ws_size,
                              hipStream_t stream) {
    char* ws = (char*)d_ws;

    int*            flags = (int*)(ws + 0);
    unsigned short* xb    = (unsigned short*)(ws + 256);
    unsigned short* wqkvT = (unsigned short*)(ws + 8388864);
    unsigned short* woT   = (unsigned short*)(ws + 14680320);
    unsigned short* w1T   = (unsigned short*)(ws + 16777472);
    unsigned short* w2T   = (unsigned short*)(ws + 25166080);
    float*          bof   = (float*)(ws + 33554688);
    float*          g1f   = (float*)(ws + 33558784);
    float*          bt1f  = (float*)(ws + 33562880);
    float*          b1f   = (float*)(ws + 33566976);
    float*          b2f   = (float*)(ws + 33583360);
    float*          g2f   = (float*)(ws + 33587456);
    float*          bt2f  = (float*)(ws + 33591552);
    unsigned short* qkv   = (unsigned short*)(ws + 33595648);
    unsigned short* ao    = (unsigned short*)(ws + 256);          // reuse xb
    unsigned short* y     = (unsigned short*)(ws + 33595648);     // reuse qkv
    unsigned short* hbuf  = (unsigned short*)(ws + 41984256);
    float*          part0 = (float*)(ws + 58761472);
    float*          part1 = (float*)(ws + 75538688);
    float*          hpart0= (float*)(ws + 256);                   // reuse ao slot

    dim3 blk(256);

    DetectArgs da;
    for (int i = 0; i < 12; i++) {
        da.p[i] = (const unsigned short*)d_in[i];
        da.n[i] = in_sizes[i];
    }
    detect_kernel<<<dim3(12), blk, 0, stream>>>(da, flags);

    // x convert + small-vector converts (fused)
    VecArgs va;
    const int vidx[7] = {3, 4, 5, 7, 9, 10, 11};
    float* vdst[7] = {bof, g1f, bt1f, b1f, b2f, g2f, bt2f};
    for (int i = 0; i < 7; i++) {
        va.src[i] = d_in[vidx[i]];
        va.dst[i] = vdst[i];
        va.n[i]   = in_sizes[vidx[i]];
        va.fidx[i] = vidx[i];
    }
    conv_x_vecs_kernel<<<dim3((NT * D_ + 255) / 256), blk, 0, stream>>>(
        d_in[0], xb, NT * D_, va, flags);

    // 4 weight transposes (fused via z-sections)
    TArgs ta;
    ta.src[0] = d_in[1]; ta.dst[0] = wqkvT; ta.K[0] = D_;  ta.N[0] = 3 * D_; ta.fidx[0] = 1;
    ta.src[1] = d_in[2]; ta.dst[1] = woT;   ta.K[1] = D_;  ta.N[1] = D_;     ta.fidx[1] = 2;
    ta.src[2] = d_in[6]; ta.dst[2] = w1T;   ta.K[2] = D_;  ta.N[2] = FF_;    ta.fidx[2] = 6;
    ta.src[3] = d_in[8]; ta.dst[3] = w2T;   ta.K[3] = FF_; ta.N[3] = D_;     ta.fidx[3] = 8;
    ta.start[0] = 0;
    for (int wI = 0; wI < 4; wI++)
        ta.start[wI + 1] = ta.start[wI] + (ta.K[wI] / 32) * (ta.N[wI] / 32);
    conv_t_all_kernel<<<dim3(ta.start[4]), blk, 0, stream>>>(ta, flags);

    // 1) qkv = x @ w_qkv, Q part pre-scaled by KLOG2E
    gemm128_kernel<false, false, 0, false, true>
        <<<dim3(NT / 128, 3072 / 128), blk, 0, stream>>>(
            xb, wqkvT, nullptr, nullptr, nullptr, flags, qkv, NT, 3072, 1024);

    // 2) attention -> ao bf16
    attn_kernel<<<dim3(S_ / 128, H_, B_), blk, 0, stream>>>(qkv, ao);

    // 3) wo projection, split-K x2 -> raw f32 partials
    gemm128_sk_kernel<<<dim3(NT / 128, 1024 / 128, 2), blk, 0, stream>>>(
        ao, woT, part0, part1, NT, 1024, 1024);

    // 4) y = LN(part0+part1 + b_o + x)
    ln_sum_kernel<1, false><<<dim3(NT), blk, 0, stream>>>(
        part0, part1, bof, (const unsigned short*)d_in[0], (const float*)d_in[0],
        g1f, bt1f, flags, y);

    // 5) h = relu(y @ w1 + b1)
    gemm128_kernel<true, true, 0, false, false>
        <<<dim3(NT / 128, 4096 / 128), blk, 0, stream>>>(
            y, w1T, b1f, nullptr, nullptr, flags, hbuf, NT, 4096, 1024);

    // 6) FFN2, split-K x2 -> raw f32 partials
    gemm128_sk_kernel<<<dim3(NT / 128, 1024 / 128, 2), blk, 0, stream>>>(
        hbuf, w2T, hpart0, part1, NT, 1024, 4096);

    // 7) out = LN(hpart0+part1 + b2 + y), output dtype per flags[0]
    ln_sum_kernel<2, true><<<dim3(NT), blk, 0, stream>>>(
        hpart0, part1, b2f, y, nullptr, g2f, bt2f, flags, d_out);
}